// Round 13
// baseline (7287.934 us; speedup 1.0000x reference)
//
#include <hip/hip_runtime.h>

// Problem constants
#define B_    32
#define T_    2048
#define F_    64
#define H_    256
#define OUT_  64
#define G3_   768           // 3*H
#define NWG1  8             // layer-1 pipeline WGs (32 h-cols each)
#define NWG2  8             // layer-2 pipeline WGs
#define TOTAL_WG (NWG1 + NWG2)
#define WGT   1024          // threads per WG (16 waves)

// Source-major packs: fp16 [par][w(8)][bb(32)][32 cols]; 2 KB contiguous per
// (par, w). h1 depth 4 (64 KB), h2 depth 2 (32 KB).
#define PBLK   1024                              // halfs per (par,w) block
#define XN_BYTES (B_ * T_ * F_ * 2)              // 8,388,608 fp16 LN(x), [T][B][F]
#define S1_OFF   XN_BYTES
#define S2_OFF   (S1_OFF + 4 * 8 * PBLK * 2)     // +64 KB
#define FLAG_OFF (S2_OFF + 2 * 8 * PBLK * 2)     // +32 KB; flags: 16 lines x 64B
#define PROG_OFF (FLAG_OFF + 1024)               // prog: 8 lines x 64B

typedef _Float16 half8 __attribute__((ext_vector_type(8)));
typedef _Float16 half4 __attribute__((ext_vector_type(4)));
typedef float    f32x4 __attribute__((ext_vector_type(4)));
typedef unsigned long long u64;

#define LD_A(p)    __hip_atomic_load((p),  __ATOMIC_RELAXED, __HIP_MEMORY_SCOPE_AGENT)
#define ST_A(p, v) __hip_atomic_store((p), (v), __ATOMIC_RELAXED, __HIP_MEMORY_SCOPE_AGENT)

__device__ __forceinline__ float sigf(float x) {
    x = fminf(fmaxf(x, -30.f), 30.f);
    return 1.f / (1.f + __expf(-x));
}
__device__ __forceinline__ float tanhfast(float x) {
    x = fminf(fmaxf(x, -15.f), 15.f);
    float e = __expf(2.f * x);
    return (e - 1.f) / (e + 1.f);
}
__device__ __forceinline__ unsigned short f16b(float f) {
    union { _Float16 h; unsigned short u; } c; c.h = (_Float16)f; return c.u;
}
// Gather 4 neighboring lanes' fp16 (jl, jl^1, jl^2, jl^3) into one u64 (LE by jl)
__device__ __forceinline__ u64 gather4(unsigned short u, int jl) {
    unsigned int p = (unsigned int)__shfl_xor((int)(unsigned int)u, 1);
    unsigned int lo32 = (jl & 1) ? ((p & 0xffffu) | ((unsigned int)u << 16))
                                 : ((unsigned int)u | (p << 16));
    unsigned int q = (unsigned int)__shfl_xor((int)lo32, 2);
    return (jl & 2) ? (((u64)lo32 << 32) | q)
                    : ((u64)lo32 | ((u64)q << 32));
}

// ---------------------------------------------------------------------------
// Init: zero packs + flags + prog, out = bias broadcast
// ---------------------------------------------------------------------------
__global__ void init_kernel(float* __restrict__ out, const float* __restrict__ bd,
                            _Float16* __restrict__ packs, unsigned int* __restrict__ flg) {
    int t = blockIdx.x * 256 + threadIdx.x;              // 4096 threads
    if (t < B_ * OUT_) out[t] = bd[t & (OUT_ - 1)];
    if (t < 1024) flg[t] = 0u;                           // flags + prog + pad
    for (int p = t; p < 6 * 8 * PBLK; p += 4096) packs[p] = (_Float16)0.f;
}

// ---------------------------------------------------------------------------
// LayerNorm over F=64, fp16 output TRANSPOSED to [T][B][F].
// ---------------------------------------------------------------------------
__global__ __launch_bounds__(256) void ln_kernel(const float* __restrict__ x,
                                                 const float* __restrict__ gamma,
                                                 const float* __restrict__ beta,
                                                 _Float16* __restrict__ xn) {
    const int tid = threadIdx.x;
    const int r = tid >> 4, q = tid & 15;
    const size_t row = (size_t)blockIdx.x * 16 + r;      // = b*T + t
    const int b = (int)(row >> 11);
    const int t = (int)(row & 2047);
    const float4 v  = *(const float4*)(x + row * F_ + q * 4);
    const float4 g  = *(const float4*)(gamma + q * 4);
    const float4 be = *(const float4*)(beta + q * 4);
    float s = v.x + v.y + v.z + v.w;
    s += __shfl_xor(s, 1, 16); s += __shfl_xor(s, 2, 16);
    s += __shfl_xor(s, 4, 16); s += __shfl_xor(s, 8, 16);
    const float mu = s * (1.f / 64.f);
    const float dx = v.x - mu, dy = v.y - mu, dz = v.z - mu, dw = v.w - mu;
    float qq = dx * dx + dy * dy + dz * dz + dw * dw;
    qq += __shfl_xor(qq, 1, 16); qq += __shfl_xor(qq, 2, 16);
    qq += __shfl_xor(qq, 4, 16); qq += __shfl_xor(qq, 8, 16);
    const float rs = rsqrtf(qq * (1.f / 64.f) + 1e-3f);
    half4 o;
    o[0] = (_Float16)(dx * rs * g.x + be.x);
    o[1] = (_Float16)(dy * rs * g.y + be.y);
    o[2] = (_Float16)(dz * rs * g.z + be.z);
    o[3] = (_Float16)(dw * rs * g.w + be.w);
    *(half4*)(xn + ((size_t)t * B_ + b) * F_ + q * 4) = o;
}

// ---------------------------------------------------------------------------
// Dual-pipeline persistent GRU. 8+8 WGs x 1024 threads (16 waves), 32 h-cols
// per WG: fan-in per wait = 8 sources (was 16), pack blocks 2 KB contiguous.
// R10 publish protocol: stores -> per-wave vmcnt drain -> __syncthreads ->
// tid0 flag store. Narrow per-thread flag polls (wave-coalesced).
// ---------------------------------------------------------------------------
__global__ __launch_bounds__(WGT) void gru_main(
    const _Float16* __restrict__ xn,
    const float* __restrict__ k1, const float* __restrict__ rk1,
    const float* __restrict__ b1, const float* __restrict__ k2,
    const float* __restrict__ rk2, const float* __restrict__ b2,
    const float* __restrict__ wd, float* __restrict__ out,
    _Float16* __restrict__ p1, _Float16* __restrict__ p2,
    unsigned int* __restrict__ flags, unsigned int* __restrict__ prog) {
    const int tid  = threadIdx.x;
    const int lane = tid & 63;
    const int wave = tid >> 6;           // 16 waves
    const int mt   = wave & 1;
    const int nt   = wave >> 1;          // 0..7
    const int ln   = lane & 15;
    const int quad = lane >> 4;

    __shared__ _Float16 h1s[32][264];    // 528B rows
    __shared__ _Float16 h2s[32][264];
    __shared__ float Cs[2][32][100];     // 96 gate cols + pad
    __shared__ float hs[32][32];

    const int  lc    = nt * 16 + ln;     // 0..127
    const bool valid = (lc < 96);
    const int  gate  = lc >> 5;          // 0..2
    const int  hidx  = lc & 31;
    const int  jl    = tid & 31;         // gate-phase col 0..31
    const int  bb    = tid >> 5;         // gate-phase batch 0..31
    const int  m     = mt * 16 + ln;     // batch row for A fragments

    if (blockIdx.x < NWG1) {
        // ================= L1 pipeline =================
        const int w    = blockIdx.x;     // 0..7, owns h1 cols w*32..w*32+32
        const int gcol = valid ? (gate * H_ + w * 32 + hidx) : 0;
        half8 fk1[2], frk1[8];
#pragma unroll
        for (int ks = 0; ks < 2; ++ks) {
            half8 f;
#pragma unroll
            for (int j = 0; j < 8; ++j) {
                const float v = k1[(ks * 32 + quad * 8 + j) * G3_ + gcol];
                f[j] = valid ? (_Float16)v : (_Float16)0.f;
            }
            fk1[ks] = f;
        }
#pragma unroll
        for (int ks = 0; ks < 8; ++ks) {
            half8 f;
#pragma unroll
            for (int j = 0; j < 8; ++j) {
                const float v = rk1[(ks * 32 + quad * 8 + j) * G3_ + gcol];
                f[j] = valid ? (_Float16)v : (_Float16)0.f;
            }
            frk1[ks] = f;
        }
        const int gc = w * 32 + jl;
        const float bxz = b1[gc],       bxr = b1[H_ + gc],       bxh = b1[2 * H_ + gc];
        const float bhz = b1[G3_ + gc], bhr = b1[G3_ + H_ + gc], bhh = b1[G3_ + 2 * H_ + gc];
        float h1m = 0.f;

        // staging map: 128 threads (2 waves) per source WG, 2 KB block
        const int w2   = tid >> 7;                 // source WG 0..7
        const int t128 = tid & 127;
        const unsigned* f1p = flags + w2 * 16;     // h1flag[w2]
        const unsigned* f2p = prog  + w2 * 16;     // L2 progress (back-pressure)

        for (int i = 0; i < T_; ++i) {
            // xproj (no cross-WG dep) before polling
            f32x4 c0 = {0.f, 0.f, 0.f, 0.f};
            {
                half8 ax0 = *(const half8*)(xn + ((size_t)i * B_ + m) * F_ + quad * 8);
                half8 ax1 = *(const half8*)(xn + ((size_t)i * B_ + m) * F_ + 32 + quad * 8);
                c0 = __builtin_amdgcn_mfma_f32_16x16x32_f16(ax0, fk1[0], c0, 0, 0, 0);
                c0 = __builtin_amdgcn_mfma_f32_16x16x32_f16(ax1, fk1[1], c0, 0, 0, 0);
            }
            // back-pressure first (rarely binds), then hot poll on source line
            if (i >= 4) {
                const unsigned tg2 = (unsigned)(i - 3);
                while (LD_A(f2p) < tg2) __builtin_amdgcn_s_sleep(1);
            }
            {
                const unsigned tgt1 = (unsigned)i;
                while (LD_A(f1p) < tgt1) __builtin_amdgcn_s_sleep(1);
                // coalesced 2 KB stage: parity (i-1)&3, source w2
                const u64* src = (const u64*)(p1 + (((unsigned)(i + 3) & 3u) * 8 + w2) * PBLK);
                u64 q0 = LD_A(src + t128);          // 512B dense per wave-instr
                u64 q1 = LD_A(src + 128 + t128);
                const int b0 = t128 >> 3;           // bb for q0 (0..15)
                const int cu = t128 & 7;            // 4-col unit
                *(u64*)(&h1s[b0][w2 * 32 + cu * 4])      = q0;
                *(u64*)(&h1s[b0 + 16][w2 * 32 + cu * 4]) = q1;
            }
            __syncthreads();

            f32x4 c1 = {0.f, 0.f, 0.f, 0.f};
#pragma unroll
            for (int ks = 0; ks < 8; ++ks) {
                half8 a1 = *(const half8*)(&h1s[m][ks * 32 + quad * 8]);
                c1 = __builtin_amdgcn_mfma_f32_16x16x32_f16(a1, frk1[ks], c1, 0, 0, 0);
            }
            if (valid) {
                const int r0 = mt * 16 + quad * 4;
#pragma unroll
                for (int rr = 0; rr < 4; ++rr) {
                    Cs[0][r0 + rr][lc] = c0[rr];
                    Cs[1][r0 + rr][lc] = c1[rr];
                }
            }
            __syncthreads();

            // gates + publish h1[i] (R10 protocol)
            {
                const float xz = Cs[0][bb][jl]      + bxz;
                const float xr = Cs[0][bb][32 + jl] + bxr;
                const float xh = Cs[0][bb][64 + jl] + bxh;
                const float rz = Cs[1][bb][jl]      + bhz;
                const float rr = Cs[1][bb][32 + jl] + bhr;
                const float rh = Cs[1][bb][64 + jl] + bhh;
                const float z  = sigf(xz + rz);
                const float r  = sigf(xr + rr);
                const float hh = tanhfast(xh + r * rh);
                h1m = z * h1m + (1.f - z) * hh;
                const u64 v1 = gather4(f16b(h1m), jl);
                if ((jl & 3) == 0)
                    ST_A((u64*)(p1 + ((unsigned)(i & 3) * 8 + w) * PBLK + bb * 32 + jl), v1);
                asm volatile("s_waitcnt vmcnt(0)" ::: "memory");
            }
            __syncthreads();
            if (tid == 0) ST_A(&flags[w * 16], (unsigned)(i + 1));
        }
    } else {
        // ================= L2 pipeline =================
        const int w    = blockIdx.x - NWG1;        // 0..7, owns h2 cols w*32..
        const int gcol = valid ? (gate * H_ + w * 32 + hidx) : 0;
        half8 fk2[8], frk2[8];
#pragma unroll
        for (int ks = 0; ks < 8; ++ks) {
            half8 f2, f3;
#pragma unroll
            for (int j = 0; j < 8; ++j) {
                const int k = ks * 32 + quad * 8 + j;
                const float v2 = k2 [k * G3_ + gcol];
                const float v3 = rk2[k * G3_ + gcol];
                f2[j] = valid ? (_Float16)v2 : (_Float16)0.f;
                f3[j] = valid ? (_Float16)v3 : (_Float16)0.f;
            }
            fk2[ks] = f2; frk2[ks] = f3;
        }
        const int gc = w * 32 + jl;
        const float bxz = b2[gc],       bxr = b2[H_ + gc],       bxh = b2[2 * H_ + gc];
        const float bhz = b2[G3_ + gc], bhr = b2[G3_ + H_ + gc], bhh = b2[G3_ + 2 * H_ + gc];
        float h2m = 0.f;

        // staging map: pk 0 = h1[t] (512 thr), pk 1 = h2[t-1] (512 thr);
        // 64 threads (1 wave) per source, 2 KB block, 4 dense 512B instrs
        const int pk  = tid >> 9;
        const int tt  = tid & 511;
        const int w2  = tt >> 6;
        const int l64 = tt & 63;
        const unsigned* fp = pk ? (flags + (8 + w2) * 16) : (flags + w2 * 16);

        for (int t = 0; t < T_; ++t) {
            // poll own source, coalesced stage of its block
            {
                const unsigned tgt = pk ? (unsigned)t : (unsigned)(t + 1);
                while (LD_A(fp) < tgt) __builtin_amdgcn_s_sleep(1);
                const u64* src = pk
                    ? (const u64*)(p2 + (((unsigned)(t + 1) & 1u) * 8 + w2) * PBLK)
                    : (const u64*)(p1 + (((unsigned)t & 3u) * 8 + w2) * PBLK);
                u64 q[4];
#pragma unroll
                for (int k = 0; k < 4; ++k) q[k] = LD_A(src + k * 64 + l64);
                _Float16 (*dst)[264] = pk ? h2s : h1s;
#pragma unroll
                for (int k = 0; k < 4; ++k) {
                    const int idx = k * 64 + l64;
                    *(u64*)(&dst[idx >> 3][w2 * 32 + (idx & 7) * 4]) = q[k];
                }
            }
            __syncthreads();
            if (tid == 0) ST_A(&prog[w * 16], (unsigned)(t + 1));  // staged h1[t]

            f32x4 c2 = {0.f, 0.f, 0.f, 0.f};
            f32x4 c3 = c2;
#pragma unroll
            for (int ks = 0; ks < 8; ++ks) {
                half8 a1 = *(const half8*)(&h1s[m][ks * 32 + quad * 8]);
                half8 a2 = *(const half8*)(&h2s[m][ks * 32 + quad * 8]);
                c2 = __builtin_amdgcn_mfma_f32_16x16x32_f16(a1, fk2[ks],  c2, 0, 0, 0);
                c3 = __builtin_amdgcn_mfma_f32_16x16x32_f16(a2, frk2[ks], c3, 0, 0, 0);
            }
            if (valid) {
                const int r0 = mt * 16 + quad * 4;
#pragma unroll
                for (int rr = 0; rr < 4; ++rr) {
                    Cs[0][r0 + rr][lc] = c2[rr];
                    Cs[1][r0 + rr][lc] = c3[rr];
                }
            }
            __syncthreads();

            // gates + publish h2[t] (R10 protocol)
            {
                const float xz = Cs[0][bb][jl]      + bxz;
                const float xr = Cs[0][bb][32 + jl] + bxr;
                const float xh = Cs[0][bb][64 + jl] + bxh;
                const float rz = Cs[1][bb][jl]      + bhz;
                const float rr = Cs[1][bb][32 + jl] + bhr;
                const float rh = Cs[1][bb][64 + jl] + bhh;
                const float z  = sigf(xz + rz);
                const float r  = sigf(xr + rr);
                const float hh = tanhfast(xh + r * rh);
                h2m = z * h2m + (1.f - z) * hh;
                const u64 v2 = gather4(f16b(h2m), jl);
                if ((jl & 3) == 0)
                    ST_A((u64*)(p2 + ((unsigned)(t & 1) * 8 + w) * PBLK + bb * 32 + jl), v2);
                asm volatile("s_waitcnt vmcnt(0)" ::: "memory");
            }
            __syncthreads();
            if (tid == 0) ST_A(&flags[(8 + w) * 16], (unsigned)(t + 1));
        }

        // ---- final dense: out[b][o] += sum_j h2[b][32w+j] * wd[32w+j][o]
        hs[bb][jl] = h2m;                // h2m = h2[T-1]
        __syncthreads();
        const int o  = tid & 63;
        const int bq = tid >> 6;         // 0..15
        for (int pass = 0; pass < 2; ++pass) {
            const int b = pass * 16 + bq;
            float acc = 0.f;
#pragma unroll
            for (int j = 0; j < 32; ++j) acc += hs[b][j] * wd[(w * 32 + j) * OUT_ + o];
            atomicAdd(&out[b * OUT_ + o], acc);
        }
    }
}

// ---------------------------------------------------------------------------
extern "C" void kernel_launch(void* const* d_in, const int* in_sizes, int n_in,
                              void* d_out, int out_size, void* d_ws, size_t ws_size,
                              hipStream_t stream) {
    const float* x     = (const float*)d_in[0];
    const float* gamma = (const float*)d_in[1];
    const float* beta  = (const float*)d_in[2];
    const float* k1    = (const float*)d_in[3];
    const float* rk1   = (const float*)d_in[4];
    const float* b1    = (const float*)d_in[5];
    const float* k2    = (const float*)d_in[6];
    const float* rk2   = (const float*)d_in[7];
    const float* b2    = (const float*)d_in[8];
    const float* wd    = (const float*)d_in[9];
    const float* bd    = (const float*)d_in[10];
    float* out = (float*)d_out;

    char* ws = (char*)d_ws;
    _Float16*     xn    = (_Float16*)ws;
    _Float16*     p1    = (_Float16*)(ws + S1_OFF);
    _Float16*     p2    = (_Float16*)(ws + S2_OFF);
    unsigned int* flags = (unsigned int*)(ws + FLAG_OFF);
    unsigned int* prog  = (unsigned int*)(ws + PROG_OFF);

    hipLaunchKernelGGL(init_kernel, dim3(16), dim3(256), 0, stream, out, bd, p1, flags);
    hipLaunchKernelGGL(ln_kernel, dim3(B_ * T_ / 16), dim3(256), 0, stream, x, gamma, beta, xn);

    void* args[] = {(void*)&xn, (void*)&k1, (void*)&rk1, (void*)&b1, (void*)&k2,
                    (void*)&rk2, (void*)&b2, (void*)&wd, (void*)&out,
                    (void*)&p1, (void*)&p2, (void*)&flags, (void*)&prog};
    hipLaunchCooperativeKernel((void*)gru_main, dim3(TOTAL_WG), dim3(WGT), args, 0, stream);
}